// Round 8
// baseline (248.671 us; speedup 1.0000x reference)
//
#include <hip/hip_runtime.h>
#include <hip/hip_bf16.h>
#include <math.h>

#define D 128
#define WS 136            // LDS row stride in shorts
#define FS 132            // LDS row stride in floats
#define PB 128            // partition blocks

typedef __attribute__((ext_vector_type(8))) short bf16x8;
typedef __attribute__((ext_vector_type(4))) float f32x4;

__device__ __forceinline__ unsigned short f2bf(float f){
  return (unsigned short)((__float_as_uint(f) + 0x8000u) >> 16);
}
__device__ __forceinline__ float bf2f(unsigned short h){
  return __uint_as_float(((unsigned)h) << 16);
}
__device__ __forceinline__ float bf2f_lo(unsigned v){
  return __uint_as_float(v << 16);
}
__device__ __forceinline__ float bf2f_hi(unsigned v){
  return __uint_as_float(v & 0xFFFF0000u);
}
__device__ __forceinline__ float gelu_fast(float v){
  float u = v * v;
  float arg = v * (1.5957691216f + 0.0713548163f * u);
  arg = fminf(arg, 60.0f);
  float e = __expf(arg);
  return v * e * __builtin_amdgcn_rcpf(e + 1.0f);
}

// ---- fused: weight convert (blocks 0..47) + bucket count (blocks 48..48+PB) ----
__global__ __launch_bounds__(256) void k_prepcnt(const float* s0, const float* s1,
    const float* s2, const float* s3, const float* s4, const float* s5,
    unsigned short* dst, const int* __restrict__ edst, int* __restrict__ cnt,
    int E, int nbuck, int epb){
  __shared__ int hist[512];
  if (blockIdx.x < 48){
    int gt = blockIdx.x * 256 + threadIdx.x;
    int m = gt >> 11;
    int r = gt & 2047;
    int f = r >> 6, lane = r & 63;
    int t = f & 7, kk = f >> 3;
    int row = t * 16 + (lane & 15);
    int col = kk * 32 + (lane >> 4) * 8;
    const float* src;
    if (m == 0) src = s0; else if (m == 1) src = s1; else if (m == 2) src = s2;
    else if (m == 3) src = s3; else if (m == 4) src = s4; else src = s5;
    src += row * 128 + col;
    float4 a = *(const float4*)src;
    float4 bb = *(const float4*)(src + 4);
    bf16x8 o;
    o[0] = (short)f2bf(a.x);  o[1] = (short)f2bf(a.y);
    o[2] = (short)f2bf(a.z);  o[3] = (short)f2bf(a.w);
    o[4] = (short)f2bf(bb.x); o[5] = (short)f2bf(bb.y);
    o[6] = (short)f2bf(bb.z); o[7] = (short)f2bf(bb.w);
    int pair = m >> 1, half = m & 1;
    *(bf16x8*)(dst + (size_t)pair * 32768 + (((size_t)f * 2 + half) * 64 + lane) * 8) = o;
    return;
  }
  int blk = blockIdx.x - 48;
  for (int b = threadIdx.x; b < nbuck; b += 256) hist[b] = 0;
  __syncthreads();
  int start = blk * epb;
  int end = min(E, start + epb);
  for (int e = start + threadIdx.x; e < end; e += 256)
    atomicAdd(&hist[edst[e] >> 7], 1);
  __syncthreads();
  for (int b = threadIdx.x; b < nbuck; b += 256) cnt[blk * nbuck + b] = hist[b];
}

// ---- per-bucket parallel scan over the PB partitions (391 parallel blocks) ----
__global__ __launch_bounds__(128) void k_scanA(const int* __restrict__ cnt,
    int* __restrict__ offs_rel, int* __restrict__ tot, int nbuck){
  __shared__ int sm[128];
  int b = blockIdx.x, t = threadIdx.x;
  int v = cnt[t * nbuck + b];
  sm[t] = v; __syncthreads();
  for (int ofs = 1; ofs < 128; ofs <<= 1){
    int u = (t >= ofs) ? sm[t - ofs] : 0;
    __syncthreads();
    sm[t] += u;
    __syncthreads();
  }
  offs_rel[t * nbuck + b] = sm[t] - v;
  if (t == 127) tot[b] = sm[127];
}

// ---- bucket scatter (LDS-only atomics); bucket bases computed in-block ----
__global__ __launch_bounds__(256) void k_pscatter(const int* __restrict__ esrc,
    const int* __restrict__ edst, const int* __restrict__ offs_rel,
    const int* __restrict__ tot, unsigned* __restrict__ ebuf,
    int E, int nbuck, int epb){
  __shared__ int stot[512];
  __shared__ int loff[512];
  for (int b = threadIdx.x; b < nbuck; b += 256) stot[b] = tot[b];
  __syncthreads();
  for (int b = threadIdx.x; b < nbuck; b += 256){
    int s = 0;
    for (int j = 0; j < b; j++) s += stot[j];
    loff[b] = s + offs_rel[blockIdx.x * nbuck + b];
  }
  __syncthreads();
  int start = blockIdx.x * epb;
  int end = min(E, start + epb);
  for (int e = start + threadIdx.x; e < end; e += 256){
    int s = esrc[e], d = edst[e];
    int b = d >> 7;
    int pos = atomicAdd(&loff[b], 1);
    ebuf[pos] = (unsigned)s | ((unsigned)(d & 127) << 16);   // N < 65536 assumed
  }
}

// ---- fused: per-bucket counting sort -> csr/off (blocks < nbuck)
//      + input layer GEMM (blocks >= nbuck) ----
__global__ __launch_bounds__(256) void k_csrin(
    const unsigned* __restrict__ ebuf, const int* __restrict__ tot,
    int* __restrict__ off, int* __restrict__ csr,
    const float* __restrict__ x, const unsigned short* __restrict__ wp,
    const float* __restrict__ scb, const float* __restrict__ dpb,
    unsigned short* __restrict__ sbuf, unsigned short* __restrict__ hbuf,
    int N, int E, int nbuck){
  __shared__ int cnt[128], pref[128], curs[128];
  __shared__ int stot[512], red[256];
  __shared__ unsigned short tile[64 * WS];
  int tid = threadIdx.x;
  if ((int)blockIdx.x < nbuck){
    int b = blockIdx.x;
    for (int j = tid; j < nbuck; j += 256) stot[j] = tot[j];
    __syncthreads();
    int part = 0;
    for (int j = tid; j < b; j += 256) part += stot[j];
    red[tid] = part;
    __syncthreads();
    for (int ofs = 128; ofs > 0; ofs >>= 1){
      if (tid < ofs) red[tid] += red[tid + ofs];
      __syncthreads();
    }
    int start = red[0];
    int end = start + stot[b];
    if (tid < 128) cnt[tid] = 0;
    __syncthreads();
    for (int e = start + tid; e < end; e += 256)
      atomicAdd(&cnt[ebuf[e] >> 16], 1);
    __syncthreads();
    if (tid < 128) pref[tid] = cnt[tid];
    __syncthreads();
    for (int ofs = 1; ofs < 128; ofs <<= 1){
      int v = 0;
      if (tid < 128 && tid >= ofs) v = pref[tid - ofs];
      __syncthreads();
      if (tid < 128) pref[tid] += v;
      __syncthreads();
    }
    if (tid < 128){
      int ex = pref[tid] - cnt[tid];
      curs[tid] = ex;
      int node = b * 128 + tid;
      if (node < N) off[node] = start + ex;
    }
    if (b == 0 && tid == 0) off[N] = E;
    __syncthreads();
    for (int e = start + tid; e < end; e += 256){
      unsigned u = ebuf[e];
      int d = u >> 16;
      int p = atomicAdd(&curs[d], 1);
      csr[start + p] = (int)(u & 0xFFFFu);
    }
    return;
  }
  // ---- input GEMM part ----
  int bx = blockIdx.x - nbuck;
  int w = tid >> 6, lane = tid & 63, quad = lane >> 4, l16 = lane & 15;
  int nbb = bx * 64;
  int nb = nbb + w * 16;
  int arow = min(nb + l16, N - 1);
  f32x4 acc[2][8];
  #pragma unroll
  for (int m = 0; m < 2; m++)
    #pragma unroll
    for (int t = 0; t < 8; t++) acc[m][t] = (f32x4){0.f, 0.f, 0.f, 0.f};
  #pragma unroll
  for (int kk = 0; kk < 4; kk++){
    const float* xp = x + (size_t)arow * D + kk * 32 + quad * 8;
    float4 xa = *(const float4*)xp;
    float4 xb = *(const float4*)(xp + 4);
    bf16x8 a;
    a[0] = (short)f2bf(xa.x); a[1] = (short)f2bf(xa.y);
    a[2] = (short)f2bf(xa.z); a[3] = (short)f2bf(xa.w);
    a[4] = (short)f2bf(xb.x); a[5] = (short)f2bf(xb.y);
    a[6] = (short)f2bf(xb.z); a[7] = (short)f2bf(xb.w);
    #pragma unroll
    for (int t = 0; t < 8; t++){
      size_t fo = (((size_t)(kk * 8 + t) * 2) * 64 + lane) * 8;
      bf16x8 b0 = *(const bf16x8*)(wp + fo);
      bf16x8 b1 = *(const bf16x8*)(wp + fo + 512);
      acc[0][t] = __builtin_amdgcn_mfma_f32_16x16x32_bf16(a, b0, acc[0][t], 0, 0, 0);
      acc[1][t] = __builtin_amdgcn_mfma_f32_16x16x32_bf16(a, b1, acc[1][t], 0, 0, 0);
    }
  }
  #pragma unroll
  for (int m = 0; m < 2; m++){
    const float* bias = m ? dpb : scb;
    #pragma unroll
    for (int t = 0; t < 8; t++){
      float bv = bias[t * 16 + l16];
      #pragma unroll
      for (int r = 0; r < 4; r++){
        int nl = w * 16 + quad * 4 + r;
        float v = acc[m][t][r] + bv;
        if (m) v = gelu_fast(v);
        tile[nl * WS + t * 16 + l16] = f2bf(v);
      }
    }
    __syncthreads();
    unsigned short* dst = m ? hbuf : sbuf;
    #pragma unroll
    for (int i = 0; i < 4; i++){
      int c = tid + 256 * i;
      int nl = c >> 4, j = c & 15;
      int node = nbb + nl;
      if (node < N)
        *(bf16x8*)(dst + (size_t)node * D + j * 8) = *(const bf16x8*)(tile + nl * WS + j * 8);
    }
    __syncthreads();
  }
}

// ---- mean aggregation v4: quarter-wave owns 2 sequential nodes whose CSR
//      ranges are contiguous; merged stream, 8-deep masked windows,
//      software-pipelined csr prefetch ----
__global__ __launch_bounds__(256) void k_agg3(const unsigned short* __restrict__ h,
    const int* __restrict__ off, const int* __restrict__ csr,
    unsigned short* __restrict__ mbuf, int N){
  int tid = threadIdx.x;
  int wq = tid >> 4;
  int l16 = tid & 15;
  int n0 = blockIdx.x * 32 + wq * 2;
  if (n0 >= N) return;
  int n1v = (n0 + 1 < N);
  int s0 = off[n0];
  int split = off[n0 + 1];
  int e1 = n1v ? off[n0 + 2] : split;
  float aall[8], ahi[8];
  #pragma unroll
  for (int c = 0; c < 8; c++){ aall[c] = 0.f; ahi[c] = 0.f; }
  if (e1 > s0){
    int nn[8];
    #pragma unroll
    for (int i = 0; i < 8; i++) nn[i] = csr[min(s0 + i, e1 - 1)];
    for (int e = s0; e < e1; e += 8){
      uint4 v[8];
      #pragma unroll
      for (int i = 0; i < 8; i++)
        v[i] = *(const uint4*)(h + (size_t)nn[i] * D + l16 * 8);
      #pragma unroll
      for (int i = 0; i < 8; i++) nn[i] = csr[min(e + 8 + i, e1 - 1)];
      #pragma unroll
      for (int i = 0; i < 8; i++){
        float mv = (e + i < e1) ? 1.f : 0.f;
        float mh = (e + i >= split) ? mv : 0.f;
        aall[0] += mv * bf2f_lo(v[i].x); ahi[0] += mh * bf2f_lo(v[i].x);
        aall[1] += mv * bf2f_hi(v[i].x); ahi[1] += mh * bf2f_hi(v[i].x);
        aall[2] += mv * bf2f_lo(v[i].y); ahi[2] += mh * bf2f_lo(v[i].y);
        aall[3] += mv * bf2f_hi(v[i].y); ahi[3] += mh * bf2f_hi(v[i].y);
        aall[4] += mv * bf2f_lo(v[i].z); ahi[4] += mh * bf2f_lo(v[i].z);
        aall[5] += mv * bf2f_hi(v[i].z); ahi[5] += mh * bf2f_hi(v[i].z);
        aall[6] += mv * bf2f_lo(v[i].w); ahi[6] += mh * bf2f_lo(v[i].w);
        aall[7] += mv * bf2f_hi(v[i].w); ahi[7] += mh * bf2f_hi(v[i].w);
      }
    }
  }
  {
    int deg0 = split - s0;
    float inv = 1.0f / (float)(deg0 > 1 ? deg0 : 1);
    uint4 o;
    o.x = ((unsigned)f2bf((aall[1] - ahi[1]) * inv) << 16) | f2bf((aall[0] - ahi[0]) * inv);
    o.y = ((unsigned)f2bf((aall[3] - ahi[3]) * inv) << 16) | f2bf((aall[2] - ahi[2]) * inv);
    o.z = ((unsigned)f2bf((aall[5] - ahi[5]) * inv) << 16) | f2bf((aall[4] - ahi[4]) * inv);
    o.w = ((unsigned)f2bf((aall[7] - ahi[7]) * inv) << 16) | f2bf((aall[6] - ahi[6]) * inv);
    *(uint4*)(mbuf + (size_t)n0 * D + l16 * 8) = o;
  }
  if (n1v){
    int deg1 = e1 - split;
    float inv = 1.0f / (float)(deg1 > 1 ? deg1 : 1);
    uint4 o;
    o.x = ((unsigned)f2bf(ahi[1] * inv) << 16) | f2bf(ahi[0] * inv);
    o.y = ((unsigned)f2bf(ahi[3] * inv) << 16) | f2bf(ahi[2] * inv);
    o.z = ((unsigned)f2bf(ahi[5] * inv) << 16) | f2bf(ahi[4] * inv);
    o.w = ((unsigned)f2bf(ahi[7] * inv) << 16) | f2bf(ahi[6] * inv);
    *(uint4*)(mbuf + (size_t)(n0 + 1) * D + l16 * 8) = o;
  }
}

// ---- SAGE layer GEMM: 16 nodes/wave, 64/block ----
__global__ __launch_bounds__(256) void k_g(
    const unsigned short* __restrict__ hin, const unsigned short* __restrict__ mbuf,
    const unsigned short* __restrict__ wp,
    const float* __restrict__ lb, const float* __restrict__ gamma,
    const float* __restrict__ beta,
    const unsigned short* __restrict__ sbuf,
    unsigned short* __restrict__ hout, float* __restrict__ fout, int N, int mode){
  extern __shared__ char smraw[];
  unsigned short* stile = (unsigned short*)smraw;
  float* ftile = (float*)smraw;
  int tid = threadIdx.x, w = tid >> 6, lane = tid & 63, quad = lane >> 4, l16 = lane & 15;
  int nbb = blockIdx.x * 64;
  int nb = nbb + w * 16;
  int arow = min(nb + l16, N - 1);
  f32x4 acc[8];
  #pragma unroll
  for (int t = 0; t < 8; t++) acc[t] = (f32x4){0.f, 0.f, 0.f, 0.f};
  #pragma unroll
  for (int kk = 0; kk < 4; kk++){
    int co = kk * 32 + quad * 8;
    bf16x8 am = *(const bf16x8*)(mbuf + (size_t)arow * D + co);
    bf16x8 ah = *(const bf16x8*)(hin + (size_t)arow * D + co);
    #pragma unroll
    for (int t = 0; t < 8; t++){
      size_t fo = (((size_t)(kk * 8 + t) * 2) * 64 + lane) * 8;
      bf16x8 bl = *(const bf16x8*)(wp + fo);
      bf16x8 br = *(const bf16x8*)(wp + fo + 512);
      acc[t] = __builtin_amdgcn_mfma_f32_16x16x32_bf16(am, bl, acc[t], 0, 0, 0);
      acc[t] = __builtin_amdgcn_mfma_f32_16x16x32_bf16(ah, br, acc[t], 0, 0, 0);
    }
  }
  float lbv[8], gv[8], bv[8];
  #pragma unroll
  for (int t = 0; t < 8; t++){
    lbv[t] = lb[t * 16 + l16];
    gv[t] = gamma[t * 16 + l16];
    bv[t] = beta[t * 16 + l16];
  }
  float mu[4], rs[4];
  #pragma unroll
  for (int r = 0; r < 4; r++){
    float s = 0.f, qq = 0.f;
    #pragma unroll
    for (int t = 0; t < 8; t++){
      float v = acc[t][r] + lbv[t];
      acc[t][r] = v;
      s += v; qq += v * v;
    }
    s += __shfl_xor(s, 1); qq += __shfl_xor(qq, 1);
    s += __shfl_xor(s, 2); qq += __shfl_xor(qq, 2);
    s += __shfl_xor(s, 4); qq += __shfl_xor(qq, 4);
    s += __shfl_xor(s, 8); qq += __shfl_xor(qq, 8);
    float m_ = s * (1.f / 128.f);
    mu[r] = m_;
    rs[r] = rsqrtf(qq * (1.f / 128.f) - m_ * m_ + 1e-5f);
  }
  if (mode == 0){
    #pragma unroll
    for (int t = 0; t < 8; t++)
      #pragma unroll
      for (int r = 0; r < 4; r++){
        int nl = w * 16 + quad * 4 + r;
        float v = (acc[t][r] - mu[r]) * rs[r] * gv[t] + bv[t];
        stile[nl * WS + t * 16 + l16] = f2bf(gelu_fast(v));
      }
    __syncthreads();
    #pragma unroll
    for (int i = 0; i < 4; i++){
      int c = tid + 256 * i;
      int nl = c >> 4, j = c & 15;
      int node = nbb + nl;
      if (node < N)
        *(bf16x8*)(hout + (size_t)node * D + j * 8) = *(const bf16x8*)(stile + nl * WS + j * 8);
    }
  } else {
    #pragma unroll
    for (int i = 0; i < 4; i++){
      int c = tid + 256 * i;
      int nl = c >> 4, j = c & 15;
      int node = nbb + nl;
      bf16x8 v = (bf16x8){0,0,0,0,0,0,0,0};
      if (node < N) v = *(const bf16x8*)(sbuf + (size_t)node * D + j * 8);
      *(bf16x8*)(stile + nl * WS + j * 8) = v;
    }
    __syncthreads();
    float sc[8][4];
    #pragma unroll
    for (int t = 0; t < 8; t++)
      #pragma unroll
      for (int r = 0; r < 4; r++){
        int nl = w * 16 + quad * 4 + r;
        sc[t][r] = bf2f(stile[nl * WS + t * 16 + l16]);
      }
    __syncthreads();
    #pragma unroll
    for (int t = 0; t < 8; t++)
      #pragma unroll
      for (int r = 0; r < 4; r++){
        int nl = w * 16 + quad * 4 + r;
        float v = (acc[t][r] - mu[r]) * rs[r] * gv[t] + bv[t];
        ftile[nl * FS + t * 16 + l16] = gelu_fast(v + sc[t][r]);
      }
    __syncthreads();
    #pragma unroll
    for (int i = 0; i < 8; i++){
      int c = tid + 256 * i;
      int nl = c >> 5, j = c & 31;
      int node = nbb + nl;
      if (node < N)
        *(float4*)(fout + (size_t)node * D + j * 4) = *(const float4*)(ftile + nl * FS + j * 4);
    }
  }
}

extern "C" void kernel_launch(void* const* d_in, const int* in_sizes, int n_in,
                              void* d_out, int out_size, void* d_ws, size_t ws_size,
                              hipStream_t stream){
  const float* x     = (const float*)d_in[0];
  const int*   edges = (const int*)d_in[1];
  const float* dp_w  = (const float*)d_in[2];
  const float* dp_b  = (const float*)d_in[3];
  const float* sc_w  = (const float*)d_in[4];
  const float* sc_b  = (const float*)d_in[5];
  const float* g1_lw = (const float*)d_in[6];
  const float* g1_lb = (const float*)d_in[7];
  const float* g1_rw = (const float*)d_in[8];
  const float* n1_g  = (const float*)d_in[9];
  const float* n1_b  = (const float*)d_in[10];
  const float* g2_lw = (const float*)d_in[11];
  const float* g2_lb = (const float*)d_in[12];
  const float* g2_rw = (const float*)d_in[13];
  const float* n2_g  = (const float*)d_in[14];
  const float* n2_b  = (const float*)d_in[15];

  const int N = in_sizes[0] / D;
  const int E = in_sizes[1] / 2;
  const int* esrc = edges;
  const int* edst = edges + E;
  const int nbuck = (N + 127) >> 7;
  const int epb = (E + PB - 1) / PB;

  char* base = (char*)d_ws;
  size_t cur = 0;
  auto carve = [&](size_t b) -> char* {
    char* p = base + cur;
    cur = (cur + b + 255) & ~(size_t)255;
    return p;
  };
  unsigned* ebuf  = (unsigned*)carve((size_t)E * 4);
  int* cnt        = (int*)carve((size_t)PB * nbuck * 4);
  int* offs_rel   = (int*)carve((size_t)PB * nbuck * 4);
  int* tot        = (int*)carve((size_t)nbuck * 4);
  int* off        = (int*)carve((size_t)(N + 1) * 4);
  int* csr        = (int*)carve((size_t)E * 4);
  unsigned short* wb    = (unsigned short*)carve((size_t)3 * 32768 * 2);
  unsigned short* hbuf  = (unsigned short*)carve((size_t)N * D * 2);
  unsigned short* h1buf = (unsigned short*)carve((size_t)N * D * 2);
  unsigned short* mbuf  = (unsigned short*)carve((size_t)N * D * 2);
  unsigned short* sbuf  = (unsigned short*)carve((size_t)N * D * 2);

  unsigned short* wp0 = wb;
  unsigned short* wp1 = wb + 32768;
  unsigned short* wp2 = wb + 2 * 32768;

  float* out = (float*)d_out;

  k_prepcnt<<<48 + PB, 256, 0, stream>>>(sc_w, dp_w, g1_lw, g1_rw, g2_lw, g2_rw,
                                         wb, edst, cnt, E, nbuck, epb);
  k_scanA<<<nbuck, 128, 0, stream>>>(cnt, offs_rel, tot, nbuck);
  k_pscatter<<<PB, 256, 0, stream>>>(esrc, edst, offs_rel, tot, ebuf, E, nbuck, epb);

  const int nin = (N + 63) / 64;
  k_csrin<<<nbuck + nin, 256, 0, stream>>>(ebuf, tot, off, csr,
                                           x, wp0, sc_b, dp_b, sbuf, hbuf,
                                           N, E, nbuck);

  const int nagg = (N + 31) / 32;
  k_agg3<<<nagg, 256, 0, stream>>>(hbuf, off, csr, mbuf, N);
  k_g<<<nin, 256, 17408, stream>>>(hbuf, mbuf, wp1, g1_lb, n1_g, n1_b,
                                   nullptr, h1buf, nullptr, N, 0);
  k_agg3<<<nagg, 256, 0, stream>>>(h1buf, off, csr, mbuf, N);
  k_g<<<nin, 256, 33792, stream>>>(h1buf, mbuf, wp2, g2_lb, n2_g, n2_b,
                                   sbuf, nullptr, out, N, 1);
}

// Round 9
// 236.800 us; speedup vs baseline: 1.0501x; 1.0501x over previous
//
#include <hip/hip_runtime.h>
#include <hip/hip_bf16.h>
#include <math.h>

#define D 128
#define WS 136            // LDS row stride in shorts
#define FS 132            // LDS row stride in floats
#define PB 128            // partition blocks

typedef __attribute__((ext_vector_type(8))) short bf16x8;
typedef __attribute__((ext_vector_type(4))) float f32x4;

__device__ __forceinline__ unsigned short f2bf(float f){
  return (unsigned short)((__float_as_uint(f) + 0x8000u) >> 16);
}
__device__ __forceinline__ float bf2f(unsigned short h){
  return __uint_as_float(((unsigned)h) << 16);
}
__device__ __forceinline__ float bf2f_lo(unsigned v){
  return __uint_as_float(v << 16);
}
__device__ __forceinline__ float bf2f_hi(unsigned v){
  return __uint_as_float(v & 0xFFFF0000u);
}
__device__ __forceinline__ float gelu_fast(float v){
  float u = v * v;
  float arg = v * (1.5957691216f + 0.0713548163f * u);
  arg = fminf(arg, 60.0f);
  float e = __expf(arg);
  return v * e * __builtin_amdgcn_rcpf(e + 1.0f);
}

// ---- fused: weight convert (blocks 0..47) + bucket count (blocks 48..48+PB) ----
__global__ __launch_bounds__(256) void k_prepcnt(const float* s0, const float* s1,
    const float* s2, const float* s3, const float* s4, const float* s5,
    unsigned short* dst, const int* __restrict__ edst, int* __restrict__ cnt,
    int E, int nbuck, int epb){
  __shared__ int hist[512];
  if (blockIdx.x < 48){
    int gt = blockIdx.x * 256 + threadIdx.x;
    int m = gt >> 11;
    int r = gt & 2047;
    int f = r >> 6, lane = r & 63;
    int t = f & 7, kk = f >> 3;
    int row = t * 16 + (lane & 15);
    int col = kk * 32 + (lane >> 4) * 8;
    const float* src;
    if (m == 0) src = s0; else if (m == 1) src = s1; else if (m == 2) src = s2;
    else if (m == 3) src = s3; else if (m == 4) src = s4; else src = s5;
    src += row * 128 + col;
    float4 a = *(const float4*)src;
    float4 bb = *(const float4*)(src + 4);
    bf16x8 o;
    o[0] = (short)f2bf(a.x);  o[1] = (short)f2bf(a.y);
    o[2] = (short)f2bf(a.z);  o[3] = (short)f2bf(a.w);
    o[4] = (short)f2bf(bb.x); o[5] = (short)f2bf(bb.y);
    o[6] = (short)f2bf(bb.z); o[7] = (short)f2bf(bb.w);
    int pair = m >> 1, half = m & 1;
    *(bf16x8*)(dst + (size_t)pair * 32768 + (((size_t)f * 2 + half) * 64 + lane) * 8) = o;
    return;
  }
  int blk = blockIdx.x - 48;
  for (int b = threadIdx.x; b < nbuck; b += 256) hist[b] = 0;
  __syncthreads();
  int start = blk * epb;
  int end = min(E, start + epb);
  for (int e = start + threadIdx.x; e < end; e += 256)
    atomicAdd(&hist[edst[e] >> 7], 1);
  __syncthreads();
  for (int b = threadIdx.x; b < nbuck; b += 256) cnt[blk * nbuck + b] = hist[b];
}

// ---- per-bucket parallel scan over the PB partitions ----
__global__ __launch_bounds__(128) void k_scanA(const int* __restrict__ cnt,
    int* __restrict__ offs_rel, int* __restrict__ tot, int nbuck){
  __shared__ int sm[128];
  int b = blockIdx.x, t = threadIdx.x;
  int v = cnt[t * nbuck + b];
  sm[t] = v; __syncthreads();
  for (int ofs = 1; ofs < 128; ofs <<= 1){
    int u = (t >= ofs) ? sm[t - ofs] : 0;
    __syncthreads();
    sm[t] += u;
    __syncthreads();
  }
  offs_rel[t * nbuck + b] = sm[t] - v;
  if (t == 127) tot[b] = sm[127];
}

// ---- bucket scatter (LDS-only atomics); bucket bases computed in-block ----
__global__ __launch_bounds__(256) void k_pscatter(const int* __restrict__ esrc,
    const int* __restrict__ edst, const int* __restrict__ offs_rel,
    const int* __restrict__ tot, unsigned* __restrict__ ebuf,
    int E, int nbuck, int epb){
  __shared__ int stot[512];
  __shared__ int loff[512];
  for (int b = threadIdx.x; b < nbuck; b += 256) stot[b] = tot[b];
  __syncthreads();
  for (int b = threadIdx.x; b < nbuck; b += 256){
    int s = 0;
    for (int j = 0; j < b; j++) s += stot[j];
    loff[b] = s + offs_rel[blockIdx.x * nbuck + b];
  }
  __syncthreads();
  int start = blockIdx.x * epb;
  int end = min(E, start + epb);
  for (int e = start + threadIdx.x; e < end; e += 256){
    int s = esrc[e], d = edst[e];
    int b = d >> 7;
    int pos = atomicAdd(&loff[b], 1);
    ebuf[pos] = (unsigned)s | ((unsigned)(d & 127) << 16);
  }
}

// ---- fused: per-bucket counting sort -> csr/off (blocks < nbuck)
//      + input layer GEMM (blocks >= nbuck) ----
__global__ __launch_bounds__(256) void k_csrin(
    const unsigned* __restrict__ ebuf, const int* __restrict__ tot,
    int* __restrict__ off, int* __restrict__ csr,
    const float* __restrict__ x, const unsigned short* __restrict__ wp,
    const float* __restrict__ scb, const float* __restrict__ dpb,
    unsigned short* __restrict__ sbuf, unsigned short* __restrict__ hbuf,
    int N, int E, int nbuck){
  __shared__ int cnt[128], pref[128], curs[128];
  __shared__ int stot[512], red[256];
  __shared__ unsigned short tile[64 * WS];
  int tid = threadIdx.x;
  if ((int)blockIdx.x < nbuck){
    int b = blockIdx.x;
    for (int j = tid; j < nbuck; j += 256) stot[j] = tot[j];
    __syncthreads();
    int part = 0;
    for (int j = tid; j < b; j += 256) part += stot[j];
    red[tid] = part;
    __syncthreads();
    for (int ofs = 128; ofs > 0; ofs >>= 1){
      if (tid < ofs) red[tid] += red[tid + ofs];
      __syncthreads();
    }
    int start = red[0];
    int end = start + stot[b];
    if (tid < 128) cnt[tid] = 0;
    __syncthreads();
    for (int e = start + tid; e < end; e += 256)
      atomicAdd(&cnt[ebuf[e] >> 16], 1);
    __syncthreads();
    if (tid < 128) pref[tid] = cnt[tid];
    __syncthreads();
    for (int ofs = 1; ofs < 128; ofs <<= 1){
      int v = 0;
      if (tid < 128 && tid >= ofs) v = pref[tid - ofs];
      __syncthreads();
      if (tid < 128) pref[tid] += v;
      __syncthreads();
    }
    if (tid < 128){
      int ex = pref[tid] - cnt[tid];
      curs[tid] = ex;
      int node = b * 128 + tid;
      if (node < N) off[node] = start + ex;
    }
    if (b == 0 && tid == 0) off[N] = E;
    __syncthreads();
    for (int e = start + tid; e < end; e += 256){
      unsigned u = ebuf[e];
      int d = u >> 16;
      int p = atomicAdd(&curs[d], 1);
      csr[start + p] = (int)(u & 0xFFFFu);
    }
    return;
  }
  // ---- input GEMM part ----
  int bx = blockIdx.x - nbuck;
  int w = tid >> 6, lane = tid & 63, quad = lane >> 4, l16 = lane & 15;
  int nbb = bx * 64;
  int nb = nbb + w * 16;
  int arow = min(nb + l16, N - 1);
  f32x4 acc[2][8];
  #pragma unroll
  for (int m = 0; m < 2; m++)
    #pragma unroll
    for (int t = 0; t < 8; t++) acc[m][t] = (f32x4){0.f, 0.f, 0.f, 0.f};
  #pragma unroll
  for (int kk = 0; kk < 4; kk++){
    const float* xp = x + (size_t)arow * D + kk * 32 + quad * 8;
    float4 xa = *(const float4*)xp;
    float4 xb = *(const float4*)(xp + 4);
    bf16x8 a;
    a[0] = (short)f2bf(xa.x); a[1] = (short)f2bf(xa.y);
    a[2] = (short)f2bf(xa.z); a[3] = (short)f2bf(xa.w);
    a[4] = (short)f2bf(xb.x); a[5] = (short)f2bf(xb.y);
    a[6] = (short)f2bf(xb.z); a[7] = (short)f2bf(xb.w);
    #pragma unroll
    for (int t = 0; t < 8; t++){
      size_t fo = (((size_t)(kk * 8 + t) * 2) * 64 + lane) * 8;
      bf16x8 b0 = *(const bf16x8*)(wp + fo);
      bf16x8 b1 = *(const bf16x8*)(wp + fo + 512);
      acc[0][t] = __builtin_amdgcn_mfma_f32_16x16x32_bf16(a, b0, acc[0][t], 0, 0, 0);
      acc[1][t] = __builtin_amdgcn_mfma_f32_16x16x32_bf16(a, b1, acc[1][t], 0, 0, 0);
    }
  }
  #pragma unroll
  for (int m = 0; m < 2; m++){
    const float* bias = m ? dpb : scb;
    #pragma unroll
    for (int t = 0; t < 8; t++){
      float bv = bias[t * 16 + l16];
      #pragma unroll
      for (int r = 0; r < 4; r++){
        int nl = w * 16 + quad * 4 + r;
        float v = acc[m][t][r] + bv;
        if (m) v = gelu_fast(v);
        tile[nl * WS + t * 16 + l16] = f2bf(v);
      }
    }
    __syncthreads();
    unsigned short* dst = m ? hbuf : sbuf;
    #pragma unroll
    for (int i = 0; i < 4; i++){
      int c = tid + 256 * i;
      int nl = c >> 4, j = c & 15;
      int node = nbb + nl;
      if (node < N)
        *(bf16x8*)(dst + (size_t)node * D + j * 8) = *(const bf16x8*)(tile + nl * WS + j * 8);
    }
    __syncthreads();
  }
}

// ---- fused SAGE layer: phase1 quarter-wave gather of 4 nodes' means -> LDS;
//      phase2 dual-MFMA GEMM (A-mean from LDS) + LN + epilogue ----
__global__ __launch_bounds__(256) void k_gall(
    const unsigned short* __restrict__ hin,
    const int* __restrict__ off, const int* __restrict__ csr,
    const unsigned short* __restrict__ wp,
    const float* __restrict__ lb, const float* __restrict__ gamma,
    const float* __restrict__ beta,
    const unsigned short* __restrict__ sbuf,
    unsigned short* __restrict__ hout, float* __restrict__ fout, int N, int mode){
  extern __shared__ char smraw[];
  unsigned short* mtile = (unsigned short*)smraw;   // 64 x WS bf16 means (phase1/2)
  unsigned short* stile = (unsigned short*)smraw;   // reused post-barrier
  float* ftile = (float*)smraw;                     // reused post-barrier (mode1)
  int tid = threadIdx.x;
  int nbb = blockIdx.x * 64;
  // ---- phase 1: gather ----
  {
    int q = tid >> 4, l16g = tid & 15;
    int n0 = nbb + q * 4;
    int s0 = off[min(n0 + 0, N)];
    int s1 = off[min(n0 + 1, N)];
    int s2 = off[min(n0 + 2, N)];
    int s3 = off[min(n0 + 3, N)];
    int s4 = off[min(n0 + 4, N)];
    float aT[8], a1[8], a2[8], a3[8];
    #pragma unroll
    for (int c = 0; c < 8; c++){ aT[c] = 0.f; a1[c] = 0.f; a2[c] = 0.f; a3[c] = 0.f; }
    if (s4 > s0){
      int nn[8];
      #pragma unroll
      for (int i = 0; i < 8; i++) nn[i] = csr[min(s0 + i, s4 - 1)];
      for (int e = s0; e < s4; e += 8){
        uint4 v[8];
        #pragma unroll
        for (int i = 0; i < 8; i++)
          v[i] = *(const uint4*)(hin + (size_t)nn[i] * D + l16g * 8);
        #pragma unroll
        for (int i = 0; i < 8; i++) nn[i] = csr[min(e + 8 + i, s4 - 1)];
        #pragma unroll
        for (int i = 0; i < 8; i++){
          int ei = e + i;
          float mT = (ei < s4) ? 1.f : 0.f;
          float m1 = (ei >= s1) ? mT : 0.f;
          float m2 = (ei >= s2) ? mT : 0.f;
          float m3 = (ei >= s3) ? mT : 0.f;
          float fv[8];
          fv[0] = bf2f_lo(v[i].x); fv[1] = bf2f_hi(v[i].x);
          fv[2] = bf2f_lo(v[i].y); fv[3] = bf2f_hi(v[i].y);
          fv[4] = bf2f_lo(v[i].z); fv[5] = bf2f_hi(v[i].z);
          fv[6] = bf2f_lo(v[i].w); fv[7] = bf2f_hi(v[i].w);
          #pragma unroll
          for (int c = 0; c < 8; c++){
            aT[c] += mT * fv[c];
            a1[c] += m1 * fv[c];
            a2[c] += m2 * fv[c];
            a3[c] += m3 * fv[c];
          }
        }
      }
    }
    float i0 = 1.f / (float)max(s1 - s0, 1);
    float i1 = 1.f / (float)max(s2 - s1, 1);
    float i2 = 1.f / (float)max(s3 - s2, 1);
    float i3 = 1.f / (float)max(s4 - s3, 1);
    bf16x8 o0, o1, o2, o3;
    #pragma unroll
    for (int c = 0; c < 8; c++){
      o0[c] = (short)f2bf((aT[c] - a1[c]) * i0);
      o1[c] = (short)f2bf((a1[c] - a2[c]) * i1);
      o2[c] = (short)f2bf((a2[c] - a3[c]) * i2);
      o3[c] = (short)f2bf(a3[c] * i3);
    }
    *(bf16x8*)(mtile + (q * 4 + 0) * WS + l16g * 8) = o0;
    *(bf16x8*)(mtile + (q * 4 + 1) * WS + l16g * 8) = o1;
    *(bf16x8*)(mtile + (q * 4 + 2) * WS + l16g * 8) = o2;
    *(bf16x8*)(mtile + (q * 4 + 3) * WS + l16g * 8) = o3;
  }
  __syncthreads();
  // ---- phase 2: GEMM + LN + epilogue ----
  int w = tid >> 6, lane = tid & 63, quad = lane >> 4, l16 = lane & 15;
  int nb = nbb + w * 16;
  int arow = min(nb + l16, N - 1);
  int mrow = w * 16 + l16;
  bf16x8 am[4], ah[4];
  #pragma unroll
  for (int kk = 0; kk < 4; kk++){
    am[kk] = *(const bf16x8*)(mtile + mrow * WS + kk * 32 + quad * 8);
    ah[kk] = *(const bf16x8*)(hin + (size_t)arow * D + kk * 32 + quad * 8);
  }
  f32x4 acc[8];
  #pragma unroll
  for (int t = 0; t < 8; t++) acc[t] = (f32x4){0.f, 0.f, 0.f, 0.f};
  #pragma unroll
  for (int kk = 0; kk < 4; kk++){
    #pragma unroll
    for (int t = 0; t < 8; t++){
      size_t fo = (((size_t)(kk * 8 + t) * 2) * 64 + lane) * 8;
      bf16x8 bl = *(const bf16x8*)(wp + fo);
      bf16x8 br = *(const bf16x8*)(wp + fo + 512);
      acc[t] = __builtin_amdgcn_mfma_f32_16x16x32_bf16(am[kk], bl, acc[t], 0, 0, 0);
      acc[t] = __builtin_amdgcn_mfma_f32_16x16x32_bf16(ah[kk], br, acc[t], 0, 0, 0);
    }
  }
  float lbv[8], gv[8], bv[8];
  #pragma unroll
  for (int t = 0; t < 8; t++){
    lbv[t] = lb[t * 16 + l16];
    gv[t] = gamma[t * 16 + l16];
    bv[t] = beta[t * 16 + l16];
  }
  float mu[4], rs[4];
  #pragma unroll
  for (int r = 0; r < 4; r++){
    float s = 0.f, qq = 0.f;
    #pragma unroll
    for (int t = 0; t < 8; t++){
      float v = acc[t][r] + lbv[t];
      acc[t][r] = v;
      s += v; qq += v * v;
    }
    s += __shfl_xor(s, 1); qq += __shfl_xor(qq, 1);
    s += __shfl_xor(s, 2); qq += __shfl_xor(qq, 2);
    s += __shfl_xor(s, 4); qq += __shfl_xor(qq, 4);
    s += __shfl_xor(s, 8); qq += __shfl_xor(qq, 8);
    float m_ = s * (1.f / 128.f);
    mu[r] = m_;
    rs[r] = rsqrtf(qq * (1.f / 128.f) - m_ * m_ + 1e-5f);
  }
  __syncthreads();   // mean tile dead; LDS reusable for epilogue
  if (mode == 0){
    #pragma unroll
    for (int t = 0; t < 8; t++)
      #pragma unroll
      for (int r = 0; r < 4; r++){
        int nl = w * 16 + quad * 4 + r;
        float v = (acc[t][r] - mu[r]) * rs[r] * gv[t] + bv[t];
        stile[nl * WS + t * 16 + l16] = f2bf(gelu_fast(v));
      }
    __syncthreads();
    #pragma unroll
    for (int i = 0; i < 4; i++){
      int c = tid + 256 * i;
      int nl = c >> 4, j = c & 15;
      int node = nbb + nl;
      if (node < N)
        *(bf16x8*)(hout + (size_t)node * D + j * 8) = *(const bf16x8*)(stile + nl * WS + j * 8);
    }
  } else {
    #pragma unroll
    for (int i = 0; i < 4; i++){
      int c = tid + 256 * i;
      int nl = c >> 4, j = c & 15;
      int node = nbb + nl;
      bf16x8 v = (bf16x8){0,0,0,0,0,0,0,0};
      if (node < N) v = *(const bf16x8*)(sbuf + (size_t)node * D + j * 8);
      *(bf16x8*)(stile + nl * WS + j * 8) = v;
    }
    __syncthreads();
    float sc[8][4];
    #pragma unroll
    for (int t = 0; t < 8; t++)
      #pragma unroll
      for (int r = 0; r < 4; r++){
        int nl = w * 16 + quad * 4 + r;
        sc[t][r] = bf2f(stile[nl * WS + t * 16 + l16]);
      }
    __syncthreads();
    #pragma unroll
    for (int t = 0; t < 8; t++)
      #pragma unroll
      for (int r = 0; r < 4; r++){
        int nl = w * 16 + quad * 4 + r;
        float v = (acc[t][r] - mu[r]) * rs[r] * gv[t] + bv[t];
        ftile[nl * FS + t * 16 + l16] = gelu_fast(v + sc[t][r]);
      }
    __syncthreads();
    #pragma unroll
    for (int i = 0; i < 8; i++){
      int c = tid + 256 * i;
      int nl = c >> 5, j = c & 31;
      int node = nbb + nl;
      if (node < N)
        *(float4*)(fout + (size_t)node * D + j * 4) = *(const float4*)(ftile + nl * FS + j * 4);
    }
  }
}

extern "C" void kernel_launch(void* const* d_in, const int* in_sizes, int n_in,
                              void* d_out, int out_size, void* d_ws, size_t ws_size,
                              hipStream_t stream){
  const float* x     = (const float*)d_in[0];
  const int*   edges = (const int*)d_in[1];
  const float* dp_w  = (const float*)d_in[2];
  const float* dp_b  = (const float*)d_in[3];
  const float* sc_w  = (const float*)d_in[4];
  const float* sc_b  = (const float*)d_in[5];
  const float* g1_lw = (const float*)d_in[6];
  const float* g1_lb = (const float*)d_in[7];
  const float* g1_rw = (const float*)d_in[8];
  const float* n1_g  = (const float*)d_in[9];
  const float* n1_b  = (const float*)d_in[10];
  const float* g2_lw = (const float*)d_in[11];
  const float* g2_lb = (const float*)d_in[12];
  const float* g2_rw = (const float*)d_in[13];
  const float* n2_g  = (const float*)d_in[14];
  const float* n2_b  = (const float*)d_in[15];

  const int N = in_sizes[0] / D;
  const int E = in_sizes[1] / 2;
  const int* esrc = edges;
  const int* edst = edges + E;
  const int nbuck = (N + 127) >> 7;
  const int epb = (E + PB - 1) / PB;

  char* base = (char*)d_ws;
  size_t cur = 0;
  auto carve = [&](size_t b) -> char* {
    char* p = base + cur;
    cur = (cur + b + 255) & ~(size_t)255;
    return p;
  };
  unsigned* ebuf  = (unsigned*)carve((size_t)E * 4);
  int* cnt        = (int*)carve((size_t)PB * nbuck * 4);
  int* offs_rel   = (int*)carve((size_t)PB * nbuck * 4);
  int* tot        = (int*)carve((size_t)nbuck * 4);
  int* off        = (int*)carve((size_t)(N + 1) * 4);
  int* csr        = (int*)carve((size_t)E * 4);
  unsigned short* wb    = (unsigned short*)carve((size_t)3 * 32768 * 2);
  unsigned short* hbuf  = (unsigned short*)carve((size_t)N * D * 2);
  unsigned short* h1buf = (unsigned short*)carve((size_t)N * D * 2);
  unsigned short* sbuf  = (unsigned short*)carve((size_t)N * D * 2);

  unsigned short* wp0 = wb;
  unsigned short* wp1 = wb + 32768;
  unsigned short* wp2 = wb + 2 * 32768;

  float* out = (float*)d_out;

  k_prepcnt<<<48 + PB, 256, 0, stream>>>(sc_w, dp_w, g1_lw, g1_rw, g2_lw, g2_rw,
                                         wb, edst, cnt, E, nbuck, epb);
  k_scanA<<<nbuck, 128, 0, stream>>>(cnt, offs_rel, tot, nbuck);
  k_pscatter<<<PB, 256, 0, stream>>>(esrc, edst, offs_rel, tot, ebuf, E, nbuck, epb);

  const int nin = (N + 63) / 64;
  k_csrin<<<nbuck + nin, 256, 0, stream>>>(ebuf, tot, off, csr,
                                           x, wp0, sc_b, dp_b, sbuf, hbuf,
                                           N, E, nbuck);

  k_gall<<<nin, 256, 17408, stream>>>(hbuf, off, csr, wp1, g1_lb, n1_g, n1_b,
                                      nullptr, h1buf, nullptr, N, 0);
  k_gall<<<nin, 256, 33792, stream>>>(h1buf, off, csr, wp2, g2_lb, n2_g, n2_b,
                                      sbuf, nullptr, out, N, 1);
}